// Round 1
// baseline (3426.475 us; speedup 1.0000x reference)
//
#include <hip/hip_runtime.h>

// Fused persistent DOPRI5 integrator: each wave owns 16 batch rows for all
// 100 steps. y, k1..k5 live in fp32 registers (MFMA C/D layout). GEMMs use
// v_mfma_f32_16x16x32_bf16 with bf16-rounded inputs, fp32 accumulate.
// W1^T staged in LDS bf16 (stride 136 -> 16B-aligned, conflict-free-ish);
// W2 fragments resident in VGPRs. Per-wave private LDS bounce buffer does the
// C/D -> A-fragment transpose; no __syncthreads in the hot loop.

#define DT 0.01f
#define N_STEPS 100
#define LDS_STRIDE 136  // ushort units; 272B row stride

typedef __attribute__((ext_vector_type(8))) short short8;
typedef __attribute__((ext_vector_type(4))) float f32x4;

__device__ __forceinline__ unsigned short f2bf(float f) {
  unsigned u = __builtin_bit_cast(unsigned, f);
  u += 0x7fffu + ((u >> 16) & 1u);  // round-to-nearest-even
  return (unsigned short)(u >> 16);
}

__device__ __forceinline__ float fast_tanh(float x) {
  float xc = fminf(fmaxf(x, -9.f), 9.f);
  float e = __expf(2.f * xc);
  return 1.f - 2.f * __builtin_amdgcn_rcpf(e + 1.f);
}

// One f(z) evaluation: z (via zfun, C/D slots) -> k (via kfun, C/D slots).
// GEMM1: H = Z @ W1 (B from LDS), tanh; GEMM2: K = tanh(H) @ W2 (B from regs).
template <typename ZF, typename KF>
__device__ __forceinline__ void feval(unsigned short* zb, const unsigned short* w1t,
                                      const short8 (&w2f)[8][4], const float (&bias1)[8],
                                      const float (&bias2)[8], int kg, int ln, ZF zfun,
                                      KF kfun) {
  // ---- write z (bf16) to bounce buffer in row-major [16][128] ----
#pragma unroll
  for (int nt = 0; nt < 8; nt++)
#pragma unroll
    for (int r = 0; r < 4; r++)
      zb[(4 * kg + r) * LDS_STRIDE + nt * 16 + ln] = f2bf(zfun(nt * 4 + r));

  // ---- read A fragments: lane holds A[row=ln][k = ks*32 + kg*8 + j] ----
  short8 af[4];
#pragma unroll
  for (int ks = 0; ks < 4; ks++)
    af[ks] = *(const short8*)&zb[ln * LDS_STRIDE + ks * 32 + kg * 8];

  // ---- GEMM1 + bias + tanh, write h back to bounce buffer ----
#pragma unroll
  for (int nt = 0; nt < 8; nt++) {
    f32x4 acc = {0.f, 0.f, 0.f, 0.f};
#pragma unroll
    for (int ks = 0; ks < 4; ks++) {
      short8 bfrag = *(const short8*)&w1t[(nt * 16 + ln) * LDS_STRIDE + ks * 32 + kg * 8];
      acc = __builtin_amdgcn_mfma_f32_16x16x32_bf16(af[ks], bfrag, acc, 0, 0, 0);
    }
#pragma unroll
    for (int r = 0; r < 4; r++)
      zb[(4 * kg + r) * LDS_STRIDE + nt * 16 + ln] = f2bf(fast_tanh(acc[r] + bias1[nt]));
  }

  // ---- read h A-fragments ----
#pragma unroll
  for (int ks = 0; ks < 4; ks++)
    af[ks] = *(const short8*)&zb[ln * LDS_STRIDE + ks * 32 + kg * 8];

  // ---- GEMM2 (B from registers) + bias -> kfun ----
#pragma unroll
  for (int nt = 0; nt < 8; nt++) {
    f32x4 acc = {0.f, 0.f, 0.f, 0.f};
#pragma unroll
    for (int ks = 0; ks < 4; ks++)
      acc = __builtin_amdgcn_mfma_f32_16x16x32_bf16(af[ks], w2f[nt][ks], acc, 0, 0, 0);
#pragma unroll
    for (int r = 0; r < 4; r++) kfun(nt * 4 + r, acc[r] + bias2[nt]);
  }
}

__global__ __launch_bounds__(256, 1) void ode_kernel(const float* __restrict__ x,
                                                     const float* __restrict__ W1,
                                                     const float* __restrict__ b1,
                                                     const float* __restrict__ W2,
                                                     const float* __restrict__ b2,
                                                     float* __restrict__ out) {
  __shared__ unsigned short w1t[128 * LDS_STRIDE];        // W1^T bf16: [n][k]
  __shared__ unsigned short zb_all[4][16 * LDS_STRIDE];   // per-wave bounce buffers

  const int tid = threadIdx.x;
  const int wave = tid >> 6;
  const int lane = tid & 63;
  const int ln = lane & 15;   // MFMA col within tile / A row
  const int kg = lane >> 4;   // lane group

  // Stage W1^T into LDS as bf16 (one-time).
  for (int i = tid; i < 128 * 128; i += 256) {
    int k = i >> 7, n = i & 127;
    w1t[n * LDS_STRIDE + k] = f2bf(W1[i]);
  }
  __syncthreads();

  // W2 B-fragments resident in VGPRs: w2f[nt][ks] = B[k=ks*32+kg*8+j][n=nt*16+ln]
  short8 w2f[8][4];
#pragma unroll
  for (int nt = 0; nt < 8; nt++)
#pragma unroll
    for (int ks = 0; ks < 4; ks++) {
      short8 v;
#pragma unroll
      for (int j = 0; j < 8; j++)
        v[j] = (short)f2bf(W2[(ks * 32 + kg * 8 + j) * 128 + nt * 16 + ln]);
      w2f[nt][ks] = v;
    }

  float bias1[8], bias2[8];
#pragma unroll
  for (int nt = 0; nt < 8; nt++) {
    bias1[nt] = b1[nt * 16 + ln];
    bias2[nt] = b2[nt * 16 + ln];
  }

  unsigned short* zb = &zb_all[wave][0];
  const int rowbase = blockIdx.x * 64 + wave * 16;

  // State in C/D layout: slot i = nt*4 + r holds element [row=4*kg+r][col=nt*16+ln]
  float y[32], k1[32], k2[32], k3[32], k4[32], k5[32];
#pragma unroll
  for (int nt = 0; nt < 8; nt++)
#pragma unroll
    for (int r = 0; r < 4; r++)
      y[nt * 4 + r] = x[(rowbase + 4 * kg + r) * 128 + nt * 16 + ln];

#pragma unroll 1
  for (int step = 0; step < N_STEPS; step++) {
    feval(zb, w1t, w2f, bias1, bias2, kg, ln,
          [&](int i) { return y[i]; },
          [&](int i, float kv) { k1[i] = kv; });
    feval(zb, w1t, w2f, bias1, bias2, kg, ln,
          [&](int i) { return y[i] + DT * (0.2f * k1[i]); },
          [&](int i, float kv) { k2[i] = kv; });
    feval(zb, w1t, w2f, bias1, bias2, kg, ln,
          [&](int i) {
            return y[i] + DT * ((3.f / 40.f) * k1[i] + (9.f / 40.f) * k2[i]);
          },
          [&](int i, float kv) { k3[i] = kv; });
    feval(zb, w1t, w2f, bias1, bias2, kg, ln,
          [&](int i) {
            return y[i] + DT * ((44.f / 45.f) * k1[i] - (56.f / 15.f) * k2[i] +
                                (32.f / 9.f) * k3[i]);
          },
          [&](int i, float kv) { k4[i] = kv; });
    feval(zb, w1t, w2f, bias1, bias2, kg, ln,
          [&](int i) {
            return y[i] + DT * ((19372.f / 6561.f) * k1[i] - (25360.f / 2187.f) * k2[i] +
                                (64448.f / 6561.f) * k3[i] - (212.f / 729.f) * k4[i]);
          },
          [&](int i, float kv) { k5[i] = kv; });
    feval(zb, w1t, w2f, bias1, bias2, kg, ln,
          [&](int i) {
            return y[i] + DT * ((9017.f / 3168.f) * k1[i] - (355.f / 33.f) * k2[i] +
                                (46732.f / 5247.f) * k3[i] + (49.f / 176.f) * k4[i] -
                                (5103.f / 18656.f) * k5[i]);
          },
          [&](int i, float kv) {
            y[i] += DT * ((35.f / 384.f) * k1[i] + (500.f / 1113.f) * k3[i] +
                          (125.f / 192.f) * k4[i] - (2187.f / 6784.f) * k5[i] +
                          (11.f / 84.f) * kv);
          });
  }

#pragma unroll
  for (int nt = 0; nt < 8; nt++)
#pragma unroll
    for (int r = 0; r < 4; r++)
      out[(rowbase + 4 * kg + r) * 128 + nt * 16 + ln] = y[nt * 4 + r];
}

extern "C" void kernel_launch(void* const* d_in, const int* in_sizes, int n_in,
                              void* d_out, int out_size, void* d_ws, size_t ws_size,
                              hipStream_t stream) {
  const float* x = (const float*)d_in[0];
  const float* W1 = (const float*)d_in[1];
  const float* b1 = (const float*)d_in[2];
  const float* W2 = (const float*)d_in[3];
  const float* b2 = (const float*)d_in[4];
  float* out = (float*)d_out;

  dim3 grid(512), block(256);
  hipLaunchKernelGGL(ode_kernel, grid, block, 0, stream, x, W1, b1, W2, b2, out);
}